// Round 18
// baseline (59.108 us; speedup 1.0000x reference)
//
#include <hip/hip_runtime.h>

// SSIM loss, 7x7 window, VALID, (64,1,512,512) fp32.
// R18 = R17 + LDS tap-prefetch one iteration ahead (the key change):
// phase r: write staged row r+1 -> issue global loads row r+3 -> issue 7
// tap reads for row r+1 into the ALTERNATE tap set -> compute row r from
// taps read LAST phase (no lgkmcnt in front of compute; the ds_write ->
// ds_read -> use chain that pinned R12/R14/R17 at ~500cy/iter is broken).
// Tap sets + pre pairs double-buffered via static parity (p&1, unroll-time).
// Keeps: f16-packed staging, fdot2 tap math, 4 channels, barrier-free
// wave-private strips, fast rcp.

constexpr int B  = 64;
constexpr int H  = 512, W = 512;
constexpr int OH = H - 6, OW = W - 6;     // 506
constexpr int CW = 64;                    // cols per wave
constexpr int BW_ = 4 * CW;               // cols per block
constexpr int SH = 32;                    // output rows per block

typedef __fp16 h2 __attribute__((ext_vector_type(2)));

__global__ __launch_bounds__(256)
void ssim_main(const float* __restrict__ X, const float* __restrict__ Y,
               const float* __restrict__ DR, float* __restrict__ partials)
{
    const int tid  = threadIdx.x;
    const int wid  = tid >> 6;
    const int lane = tid & 63;
    const int c0   = blockIdx.x * BW_ + wid * CW;   // wave-private strip
    const int r0   = blockIdx.y * SH;
    const int b    = blockIdx.z;

    const int out_rows = min(SH, OH - r0);
    const int rows_in  = out_rows + 6;       // 32..38, block-uniform

    const float d  = DR[b];
    const float C1 = (0.01f * d) * (0.01f * d);
    const float C2 = (0.03f * d) * (0.03f * d);
    const float c1s = 2401.0f * C1;          // 49^2 * C1
    const float c2s = 2352.0f * C2;          // 48*49 * C2

    const float* __restrict__ Xb = X + (size_t)b * H * W;
    const float* __restrict__ Yb = Y + (size_t)b * H * W;

    unsigned off  = (unsigned)(r0 * W + c0 + lane);
    unsigned hoff = (unsigned)(r0 * W + min(c0 + CW + lane, W - 1));

    const bool colvalid = (c0 + lane) < OW;
    const bool is_halo  = lane < 6;

    // wave-private row buffer: packed f16 {x,y} per col, 70 used
    __shared__ h2 rbu[4][CW + 8];
    h2* const buf = rbu[wid];

    // vertical state: 4 channels {sx, sy, ss=Sxx+Syy, w=2*Sxy}, 7-row history
    float bhx[7], bhy[7], bhs[7], bhw[7];
    float vx = 0.f, vy = 0.f, vss = 0.f, vw = 0.f;
#pragma unroll
    for (int i = 0; i < 7; ++i) { bhx[i]=bhy[i]=bhs[i]=bhw[i]=0.f; }

    float acc = 0.f;

    // double-buffered tap sets (static parity) and global prefetch pairs
    h2 tA[7], tB[7];
    float2 pre0, pre1;
    float2 preh0 = make_float2(0.f,0.f), preh1 = make_float2(0.f,0.f);

    // ---- prologue ----
    // pair(0) -> stage row 0 -> taps(0) into tA ; issue pair(1), pair(2)
    {
        float2 p00; p00.x = Xb[off]; p00.y = Yb[off];
        float2 ph00 = make_float2(0.f,0.f);
        if (is_halo) { ph00.x = Xb[hoff]; ph00.y = Yb[hoff]; }
        off += W; hoff += W;
        // pair(1) -> pre1 (slot (r+1)&1 for r=0), pair(2) -> pre0
        pre1.x = Xb[off]; pre1.y = Yb[off];
        if (is_halo) { preh1.x = Xb[hoff]; preh1.y = Yb[hoff]; }
        off += W; hoff += W;
        pre0.x = Xb[off]; pre0.y = Yb[off];
        if (is_halo) { preh0.x = Xb[hoff]; preh0.y = Yb[hoff]; }
        off += W; hoff += W;

        buf[lane] = __builtin_amdgcn_cvt_pkrtz(p00.x, p00.y);
        if (is_halo) buf[CW + lane] = __builtin_amdgcn_cvt_pkrtz(ph00.x, ph00.y);
#pragma unroll
        for (int i = 0; i < 7; ++i) tA[i] = buf[lane + i];
    }

    for (int rr = 0; rr < 42; rr += 14) {
#pragma unroll
        for (int p = 0; p < 14; ++p) {
            const int r = rr + p;              // r%7 == p%7, r&1 == p&1
            if (r < rows_in) {                 // block-uniform
                // tap set holding taps(r) -- static by parity
                h2 (&tc)[7] = (p & 1) ? tB : tA;
                h2 (&tn)[7] = (p & 1) ? tA : tB;
                float2& pr = (p & 1) ? pre0 : pre1;   // pair(r+1)
                float2& ph = (p & 1) ? preh0 : preh1;

                // 1) stage row r+1; 2) issue globals for row r+3
                if (r + 1 < rows_in) {
                    buf[lane] = __builtin_amdgcn_cvt_pkrtz(pr.x, pr.y);
                    if (is_halo) buf[CW + lane] = __builtin_amdgcn_cvt_pkrtz(ph.x, ph.y);
                    if (r + 3 < rows_in) {
                        pr.x = Xb[off]; pr.y = Yb[off];
                        if (is_halo) { ph.x = Xb[hoff]; ph.y = Yb[hoff]; }
                        off += W; hoff += W;
                    }
                    // 3) issue tap reads for row r+1 (consumed next phase)
#pragma unroll
                    for (int i = 0; i < 7; ++i) tn[i] = buf[lane + i];
                }

                // 4) compute row r from taps read LAST phase (no DS wait)
                const h2 t0 = tc[0], t1 = tc[1], t2_ = tc[2], t3 = tc[3],
                         t4 = tc[4], t5 = tc[5], t6 = tc[6];

                float hss = __builtin_amdgcn_fdot2(t0, t0, 0.f, false);
                hss = __builtin_amdgcn_fdot2(t1, t1, hss, false);
                hss = __builtin_amdgcn_fdot2(t2_, t2_, hss, false);
                hss = __builtin_amdgcn_fdot2(t3, t3, hss, false);
                hss = __builtin_amdgcn_fdot2(t4, t4, hss, false);
                hss = __builtin_amdgcn_fdot2(t5, t5, hss, false);
                hss = __builtin_amdgcn_fdot2(t6, t6, hss, false);

                #define SW(t) __builtin_shufflevector(t, t, 1, 0)
                float hw = __builtin_amdgcn_fdot2(t0, SW(t0), 0.f, false);
                hw = __builtin_amdgcn_fdot2(t1, SW(t1), hw, false);
                hw = __builtin_amdgcn_fdot2(t2_, SW(t2_), hw, false);
                hw = __builtin_amdgcn_fdot2(t3, SW(t3), hw, false);
                hw = __builtin_amdgcn_fdot2(t4, SW(t4), hw, false);
                hw = __builtin_amdgcn_fdot2(t5, SW(t5), hw, false);
                hw = __builtin_amdgcn_fdot2(t6, SW(t6), hw, false);
                #undef SW

                const h2 hp = ((t0 + t1) + (t2_ + t3)) + ((t4 + t5) + t6);
                const float hx = (float)hp.x;
                const float hy = (float)hp.y;

                // vertical running 7-row window (slot p%7 holds row r-7)
                constexpr int s7[14] = {0,1,2,3,4,5,6,0,1,2,3,4,5,6};
                const int sp = s7[p];
                vx  += hx  - bhx[sp]; bhx[sp] = hx;
                vy  += hy  - bhy[sp]; bhy[sp] = hy;
                vss += hss - bhs[sp]; bhs[sp] = hss;
                vw  += hw  - bhw[sp]; bhw[sp] = hw;

                if (r >= 6 && colvalid) {
                    // S = (2 SxSy + c1s)(49*vw - 2 SxSy + c2s)
                    //   / (Sx^2+Sy^2+c1s)(49*vss - Sx^2 - Sy^2 + c2s)
                    const float p1 = vx * vy;
                    const float t1f = fmaf(2.f, p1, c1s);
                    const float t2f = fmaf(-2.f, p1, fmaf(49.f, vw, c2s));
                    const float n2 = fmaf(vy, vy, vx * vx);
                    const float b1 = n2 + c1s;
                    const float b2 = fmaf(49.f, vss, c2s) - n2;
                    const float den = b1 * b2;
                    float rc = __builtin_amdgcn_rcpf(den);
                    rc = rc * (2.f - den * rc);          // 1 Newton step
                    acc = fmaf(t1f * t2f, rc, acc);
                }
            }
        }
    }

    // block reduction: wave shfl, then cross-wave via LDS (single barrier)
    float s = acc;
#pragma unroll
    for (int o = 32; o; o >>= 1) s += __shfl_down(s, o, 64);
    __shared__ float wsum[4];
    if (lane == 0) wsum[wid] = s;
    __syncthreads();
    if (tid == 0) {
        const int bid = (blockIdx.z * gridDim.y + blockIdx.y) * gridDim.x + blockIdx.x;
        partials[bid] = wsum[0] + wsum[1] + wsum[2] + wsum[3];
    }
}

__global__ __launch_bounds__(256)
void ssim_final(const float* __restrict__ partials, int n,
                float* __restrict__ out, float inv_count)
{
    const int tid = threadIdx.x;
    float s = 0.f;
    for (int i = tid; i < n; i += 256) s += partials[i];
#pragma unroll
    for (int o = 32; o; o >>= 1) s += __shfl_down(s, o, 64);
    __shared__ float wsum[4];
    if ((tid & 63) == 0) wsum[tid >> 6] = s;
    __syncthreads();
    if (tid == 0) out[0] = 1.0f - (wsum[0] + wsum[1] + wsum[2] + wsum[3]) * inv_count;
}

extern "C" void kernel_launch(void* const* d_in, const int* in_sizes, int n_in,
                              void* d_out, int out_size, void* d_ws, size_t ws_size,
                              hipStream_t stream)
{
    const float* X  = (const float*)d_in[0];
    const float* Y  = (const float*)d_in[1];
    const float* DR = (const float*)d_in[2];
    float* out      = (float*)d_out;
    float* partials = (float*)d_ws;

    const int gx = (OW + BW_ - 1) / BW_; // 2
    const int gy = (OH + SH - 1) / SH;   // 16
    dim3 grid(gx, gy, B);                // 2048 blocks, every partial slot written
    ssim_main<<<grid, 256, 0, stream>>>(X, Y, DR, partials);

    const int n = gx * gy * B;           // 2048
    const float inv_count = 1.0f / (float)((long)B * OH * OW);
    ssim_final<<<1, 256, 0, stream>>>(partials, n, out, inv_count);
}

// Round 19
// 47.481 us; speedup vs baseline: 1.2449x; 1.2449x over previous
//
#include <hip/hip_runtime.h>

// SSIM loss, 7x7 window, VALID, (64,1,512,512) fp32.
// R19 = R14 (best f32 path, 47.7us) + dual-slot LDS row buffer with
// read-early phase order — R18's chain-break redone at ZERO VALU/VGPR cost:
//   phase r: read 7 taps of row r from slot[r&1] (staged last phase, no
//   same-phase dependency) -> stage row r+1 into slot[(r+1)&1] -> global
//   prefetch row r+3 -> compute row r.
// R18 retired (tap-set double-buffer cost +35% VALU, +20 VGPR). f16/fdot2
// retired (R17 never beat f32 R14).

constexpr int B  = 64;
constexpr int H  = 512, W = 512;
constexpr int OH = H - 6, OW = W - 6;     // 506
constexpr int CW = 64;                    // output cols per wave
constexpr int BW_ = 4 * CW;               // output cols per block (256)
constexpr int SH = 32;                    // output rows per block

__global__ __launch_bounds__(256)
void ssim_main(const float* __restrict__ X, const float* __restrict__ Y,
               const float* __restrict__ DR, float* __restrict__ partials)
{
    const int tid  = threadIdx.x;
    const int wid  = tid >> 6;
    const int lane = tid & 63;
    const int c0   = blockIdx.x * BW_ + wid * CW;   // wave-private strip
    const int r0   = blockIdx.y * SH;
    const int b    = blockIdx.z;

    const int out_rows = min(SH, OH - r0);
    const int rows_in  = out_rows + 6;       // 32..38, block-uniform

    const float d  = DR[b];
    const float C1 = (0.01f * d) * (0.01f * d);
    const float C2 = (0.03f * d) * (0.03f * d);
    const float c1s = 2401.0f * C1;          // 49^2 * C1
    const float c2s = 2352.0f * C2;          // 48*49 * C2

    const float* __restrict__ Xb = X + (size_t)b * H * W;
    const float* __restrict__ Yb = Y + (size_t)b * H * W;

    unsigned off  = (unsigned)(r0 * W + c0 + lane);
    unsigned hoff = (unsigned)(r0 * W + min(c0 + CW + lane, W - 1));

    const bool colvalid = (c0 + lane) < OW;
    const bool is_halo  = lane < 6;

    // wave-private DUAL-slot row buffer: {x,y} pairs, 70 used per slot
    __shared__ float2 rb[4][2][CW + 8];

    // vertical circular buffers (statically indexed via unroll)
    float bx[7], by[7], bxx[7], byy[7], bxy[7];
    float vsx = 0.f, vsy = 0.f, vsxx = 0.f, vsyy = 0.f, vsxy = 0.f;
#pragma unroll
    for (int i = 0; i < 7; ++i) { bx[i]=by[i]=bxx[i]=byy[i]=bxy[i]=0.f; }

    float acc = 0.f;

    // prefetch pairs by parity: pre1 holds odd rows, pre0 even rows
    float2 pre0, pre1;
    float2 preh0 = make_float2(0.f, 0.f), preh1 = make_float2(0.f, 0.f);

    // ---- prologue: row0 -> slot0 (staged), row1 -> pre1, row2 -> pre0 ----
    {
        float2 p0; p0.x = Xb[off]; p0.y = Yb[off];
        float2 ph0 = make_float2(0.f, 0.f);
        if (is_halo) { ph0.x = Xb[hoff]; ph0.y = Yb[hoff]; }
        off += W; hoff += W;
        pre1.x = Xb[off]; pre1.y = Yb[off];
        if (is_halo) { preh1.x = Xb[hoff]; preh1.y = Yb[hoff]; }
        off += W; hoff += W;
        pre0.x = Xb[off]; pre0.y = Yb[off];
        if (is_halo) { preh0.x = Xb[hoff]; preh0.y = Yb[hoff]; }
        off += W; hoff += W;

        float2* s0 = rb[wid][0];
        s0[lane] = p0;
        if (is_halo) s0[CW + lane] = ph0;
    }

    for (int rr = 0; rr < 42; rr += 14) {
#pragma unroll
        for (int p = 0; p < 14; ++p) {
            const int r = rr + p;              // r%7 == p%7, r&1 == p&1
            if (r < rows_in) {                 // block-uniform
                float2* const rslot = rb[wid][p & 1];        // row r (staged)
                float2* const wslot = rb[wid][(p & 1) ^ 1];  // row r+1 dest
                float2& pr = (p & 1) ? pre0 : pre1;          // pair(r+1)
                float2& ph = (p & 1) ? preh0 : preh1;

                // 1) issue tap reads of row r (no same-phase dependency)
                const float2 v0 = rslot[lane+0], v1 = rslot[lane+1],
                             v2 = rslot[lane+2], v3 = rslot[lane+3],
                             v4 = rslot[lane+4], v5 = rslot[lane+5],
                             v6 = rslot[lane+6];

                // 2) stage row r+1 into the other slot
                if (r + 1 < rows_in) {
                    wslot[lane] = pr;
                    if (is_halo) wslot[CW + lane] = ph;
                    // 3) issue globals for row r+3 (same parity regs)
                    if (r + 3 < rows_in) {
                        pr.x = Xb[off]; pr.y = Yb[off];
                        if (is_halo) { ph.x = Xb[hoff]; ph.y = Yb[hoff]; }
                        off += W; hoff += W;
                    }
                }

                // 4) compute row r: horizontal 7-tap sums of the 5 channels
                float hx = 0.f, hy = 0.f, hxx = 0.f, hyy = 0.f, hxy = 0.f;
                {
                    const float2 vv[7] = {v0,v1,v2,v3,v4,v5,v6};
#pragma unroll
                    for (int i = 0; i < 7; ++i) {
                        const float2 v = vv[i];
                        hx += v.x; hy += v.y;
                        hxx = fmaf(v.x, v.x, hxx);
                        hyy = fmaf(v.y, v.y, hyy);
                        hxy = fmaf(v.x, v.y, hxy);
                    }
                }

                // vertical running 7-row window (slot p%7 holds row r-7)
                constexpr int s7[14] = {0,1,2,3,4,5,6,0,1,2,3,4,5,6};
                const int sp = s7[p];
                vsx  += hx  - bx[sp];  bx[sp]  = hx;
                vsy  += hy  - by[sp];  by[sp]  = hy;
                vsxx += hxx - bxx[sp]; bxx[sp] = hxx;
                vsyy += hyy - byy[sp]; byy[sp] = hyy;
                vsxy += hxy - bxy[sp]; bxy[sp] = hxy;

                if (r >= 6 && colvalid) {
                    // S = (2 sx sy + c1s)(2(49 sxy - sx sy) + c2s)
                    //   / (sx^2+sy^2+c1s)(49(sxx+syy) - sx^2 - sy^2 + c2s)
                    const float p1 = vsx * vsy;
                    const float t1 = fmaf(2.f, p1, c1s);
                    const float q  = fmaf(49.f, vsxy, -p1);
                    const float t2 = fmaf(2.f, q, c2s);
                    const float n1 = vsx * vsx;
                    const float n2 = fmaf(vsy, vsy, n1);
                    const float b1 = n2 + c1s;
                    const float s3 = vsxx + vsyy;
                    const float b2 = fmaf(49.f, s3, c2s) - n2;
                    const float num = t1 * t2;
                    const float den = b1 * b2;
                    float rcp = __builtin_amdgcn_rcpf(den);
                    rcp = rcp * (2.f - den * rcp);      // 1 Newton step
                    acc = fmaf(num, rcp, acc);
                }
            }
        }
    }

    // block reduction: wave shfl, then cross-wave via LDS (single barrier)
    float s = acc;
#pragma unroll
    for (int o = 32; o; o >>= 1) s += __shfl_down(s, o, 64);
    __shared__ float wsum[4];
    if (lane == 0) wsum[wid] = s;
    __syncthreads();
    if (tid == 0) {
        const int bid = (blockIdx.z * gridDim.y + blockIdx.y) * gridDim.x + blockIdx.x;
        partials[bid] = wsum[0] + wsum[1] + wsum[2] + wsum[3];
    }
}

__global__ __launch_bounds__(256)
void ssim_final(const float* __restrict__ partials, int n,
                float* __restrict__ out, float inv_count)
{
    const int tid = threadIdx.x;
    float s = 0.f;
    for (int i = tid; i < n; i += 256) s += partials[i];
#pragma unroll
    for (int o = 32; o; o >>= 1) s += __shfl_down(s, o, 64);
    __shared__ float wsum[4];
    if ((tid & 63) == 0) wsum[tid >> 6] = s;
    __syncthreads();
    if (tid == 0) out[0] = 1.0f - (wsum[0] + wsum[1] + wsum[2] + wsum[3]) * inv_count;
}

extern "C" void kernel_launch(void* const* d_in, const int* in_sizes, int n_in,
                              void* d_out, int out_size, void* d_ws, size_t ws_size,
                              hipStream_t stream)
{
    const float* X  = (const float*)d_in[0];
    const float* Y  = (const float*)d_in[1];
    const float* DR = (const float*)d_in[2];
    float* out      = (float*)d_out;
    float* partials = (float*)d_ws;

    const int gx = (OW + BW_ - 1) / BW_; // 2
    const int gy = (OH + SH - 1) / SH;   // 16
    dim3 grid(gx, gy, B);                // 2048 blocks, every partial slot written
    ssim_main<<<grid, 256, 0, stream>>>(X, Y, DR, partials);

    const int n = gx * gy * B;           // 2048
    const float inv_count = 1.0f / (float)((long)B * OH * OW);
    ssim_final<<<1, 256, 0, stream>>>(partials, n, out, inv_count);
}

// Round 20
// 44.844 us; speedup vs baseline: 1.3181x; 1.0588x over previous
//
#include <hip/hip_runtime.h>

// SSIM loss, 7x7 window, VALID, (64,1,512,512) fp32.
// R20 = R12 grid (SH=64, best bench 46.9) + R19 read-early dual-slot LDS +
// PACKED-F32 channel math: MI355X's 157.3TF fp32 = 2x scalar issue via
// VOP3P (v_pk_add_f32 / v_pk_fma_f32). The (x,y) pairs are natural pk
// pairs: (hx,hy), (hxx,hyy), (vsx,vsy), (vsxx,vsyy) as float2 ext-vectors
// (clang pattern-matches <2 x float> fadd/ffma to VOP3P on gfx90a+).
// Tap core 35 -> 20 insts, vertical 10 -> 6. hxy stays scalar.

constexpr int B  = 64;
constexpr int H  = 512, W = 512;
constexpr int OH = H - 6, OW = W - 6;     // 506
constexpr int CW = 64;                    // output cols per wave
constexpr int BW_ = 4 * CW;               // output cols per block (256)
constexpr int SH = 64;                    // output rows per block

typedef float f2 __attribute__((ext_vector_type(2)));

__global__ __launch_bounds__(256)
void ssim_main(const float* __restrict__ X, const float* __restrict__ Y,
               const float* __restrict__ DR, float* __restrict__ partials)
{
    const int tid  = threadIdx.x;
    const int wid  = tid >> 6;
    const int lane = tid & 63;
    const int c0   = blockIdx.x * BW_ + wid * CW;   // wave-private strip
    const int r0   = blockIdx.y * SH;
    const int b    = blockIdx.z;

    const int out_rows = min(SH, OH - r0);
    const int rows_in  = out_rows + 6;       // <= 70, block-uniform

    const float d  = DR[b];
    const float C1 = (0.01f * d) * (0.01f * d);
    const float C2 = (0.03f * d) * (0.03f * d);
    const float c1s = 2401.0f * C1;          // 49^2 * C1
    const float c2s = 2352.0f * C2;          // 48*49 * C2

    const float* __restrict__ Xb = X + (size_t)b * H * W;
    const float* __restrict__ Yb = Y + (size_t)b * H * W;

    unsigned off  = (unsigned)(r0 * W + c0 + lane);
    unsigned hoff = (unsigned)(r0 * W + min(c0 + CW + lane, W - 1));

    const bool colvalid = (c0 + lane) < OW;
    const bool is_halo  = lane < 6;

    // wave-private DUAL-slot row buffer: {x,y} pairs, 70 used per slot
    __shared__ f2 rb[4][2][CW + 8];

    // vertical state: packed pairs P=(sx,sy), Q=(sxx,syy); scalar sxy
    f2 bP[7], bQ[7];
    float bxy[7];
    f2 P = {0.f, 0.f}, Q = {0.f, 0.f};
    float vsxy = 0.f;
#pragma unroll
    for (int i = 0; i < 7; ++i) { bP[i] = P; bQ[i] = Q; bxy[i] = 0.f; }

    float acc = 0.f;

    // prefetch pairs by parity: pre1 holds odd rows, pre0 even rows
    f2 pre0, pre1;
    f2 preh0 = {0.f, 0.f}, preh1 = {0.f, 0.f};

    // ---- prologue: row0 -> slot0 (staged), row1 -> pre1, row2 -> pre0 ----
    {
        f2 p0; p0.x = Xb[off]; p0.y = Yb[off];
        f2 ph0 = {0.f, 0.f};
        if (is_halo) { ph0.x = Xb[hoff]; ph0.y = Yb[hoff]; }
        off += W; hoff += W;
        pre1.x = Xb[off]; pre1.y = Yb[off];
        if (is_halo) { preh1.x = Xb[hoff]; preh1.y = Yb[hoff]; }
        off += W; hoff += W;
        pre0.x = Xb[off]; pre0.y = Yb[off];
        if (is_halo) { preh0.x = Xb[hoff]; preh0.y = Yb[hoff]; }
        off += W; hoff += W;

        f2* s0 = rb[wid][0];
        s0[lane] = p0;
        if (is_halo) s0[CW + lane] = ph0;
    }

    for (int rr = 0; rr < 70; rr += 14) {
#pragma unroll
        for (int p = 0; p < 14; ++p) {
            const int r = rr + p;              // r%7 == p%7, r&1 == p&1
            if (r < rows_in) {                 // block-uniform
                f2* const rslot = rb[wid][p & 1];        // row r (staged)
                f2* const wslot = rb[wid][(p & 1) ^ 1];  // row r+1 dest
                f2& pr = (p & 1) ? pre0 : pre1;          // pair(r+1)
                f2& ph = (p & 1) ? preh0 : preh1;

                // 1) issue tap reads of row r (staged last phase)
                const f2 v0 = rslot[lane+0], v1 = rslot[lane+1],
                         v2 = rslot[lane+2], v3 = rslot[lane+3],
                         v4 = rslot[lane+4], v5 = rslot[lane+5],
                         v6 = rslot[lane+6];

                // 2) stage row r+1 into the other slot
                if (r + 1 < rows_in) {
                    wslot[lane] = pr;
                    if (is_halo) wslot[CW + lane] = ph;
                    // 3) issue globals for row r+3 (same parity regs)
                    if (r + 3 < rows_in) {
                        pr.x = Xb[off]; pr.y = Yb[off];
                        if (is_halo) { ph.x = Xb[hoff]; ph.y = Yb[hoff]; }
                        off += W; hoff += W;
                    }
                }

                // 4) compute row r — packed-f32 channel math
                // (hx,hy): 6 pk_add
                const f2 s2 = ((v0 + v1) + (v2 + v3)) + ((v4 + v5) + v6);
                // (hxx,hyy): 7 pk_fma
                f2 q2 = v0 * v0;
                q2 = __builtin_elementwise_fma(v1, v1, q2);
                q2 = __builtin_elementwise_fma(v2, v2, q2);
                q2 = __builtin_elementwise_fma(v3, v3, q2);
                q2 = __builtin_elementwise_fma(v4, v4, q2);
                q2 = __builtin_elementwise_fma(v5, v5, q2);
                q2 = __builtin_elementwise_fma(v6, v6, q2);
                // hxy: scalar 7 fma
                float hxy = v0.x * v0.y;
                hxy = fmaf(v1.x, v1.y, hxy);
                hxy = fmaf(v2.x, v2.y, hxy);
                hxy = fmaf(v3.x, v3.y, hxy);
                hxy = fmaf(v4.x, v4.y, hxy);
                hxy = fmaf(v5.x, v5.y, hxy);
                hxy = fmaf(v6.x, v6.y, hxy);

                // vertical running 7-row window (slot p%7 holds row r-7)
                constexpr int s7[14] = {0,1,2,3,4,5,6,0,1,2,3,4,5,6};
                const int sp = s7[p];
                P += s2 - bP[sp];   bP[sp] = s2;     // 2 pk
                Q += q2 - bQ[sp];   bQ[sp] = q2;     // 2 pk
                vsxy += hxy - bxy[sp]; bxy[sp] = hxy;

                if (r >= 6 && colvalid) {
                    // S = (2 sx sy + c1s)(2(49 sxy - sx sy) + c2s)
                    //   / (sx^2+sy^2+c1s)(49(sxx+syy) - sx^2 - sy^2 + c2s)
                    const float vsx = P.x, vsy = P.y;
                    const float p1 = vsx * vsy;
                    const float t1 = fmaf(2.f, p1, c1s);
                    const float q  = fmaf(49.f, vsxy, -p1);
                    const float t2 = fmaf(2.f, q, c2s);
                    const float n2 = fmaf(vsy, vsy, vsx * vsx);
                    const float b1 = n2 + c1s;
                    const float s3 = Q.x + Q.y;
                    const float b2 = fmaf(49.f, s3, c2s) - n2;
                    const float num = t1 * t2;
                    const float den = b1 * b2;
                    float rcp = __builtin_amdgcn_rcpf(den);
                    rcp = rcp * (2.f - den * rcp);      // 1 Newton step
                    acc = fmaf(num, rcp, acc);
                }
            }
        }
    }

    // block reduction: wave shfl, then cross-wave via LDS (single barrier)
    float s = acc;
#pragma unroll
    for (int o = 32; o; o >>= 1) s += __shfl_down(s, o, 64);
    __shared__ float wsum[4];
    if (lane == 0) wsum[wid] = s;
    __syncthreads();
    if (tid == 0) {
        const int bid = (blockIdx.z * gridDim.y + blockIdx.y) * gridDim.x + blockIdx.x;
        partials[bid] = wsum[0] + wsum[1] + wsum[2] + wsum[3];
    }
}

__global__ __launch_bounds__(256)
void ssim_final(const float* __restrict__ partials, int n,
                float* __restrict__ out, float inv_count)
{
    const int tid = threadIdx.x;
    float s = 0.f;
    for (int i = tid; i < n; i += 256) s += partials[i];
#pragma unroll
    for (int o = 32; o; o >>= 1) s += __shfl_down(s, o, 64);
    __shared__ float wsum[4];
    if ((tid & 63) == 0) wsum[tid >> 6] = s;
    __syncthreads();
    if (tid == 0) out[0] = 1.0f - (wsum[0] + wsum[1] + wsum[2] + wsum[3]) * inv_count;
}

extern "C" void kernel_launch(void* const* d_in, const int* in_sizes, int n_in,
                              void* d_out, int out_size, void* d_ws, size_t ws_size,
                              hipStream_t stream)
{
    const float* X  = (const float*)d_in[0];
    const float* Y  = (const float*)d_in[1];
    const float* DR = (const float*)d_in[2];
    float* out      = (float*)d_out;
    float* partials = (float*)d_ws;

    const int gx = (OW + BW_ - 1) / BW_; // 2
    const int gy = (OH + SH - 1) / SH;   // 8
    dim3 grid(gx, gy, B);                // 1024 blocks, every partial slot written
    ssim_main<<<grid, 256, 0, stream>>>(X, Y, DR, partials);

    const int n = gx * gy * B;           // 1024
    const float inv_count = 1.0f / (float)((long)B * OH * OW);
    ssim_final<<<1, 256, 0, stream>>>(partials, n, out, inv_count);
}